// Round 1
// baseline (2633.451 us; speedup 1.0000x reference)
//
#include <hip/hip_runtime.h>
#include <cstdint>

#define NF 65536
#define PL 8
#define NL 4096
#define PPL 128

__device__ __forceinline__ float sigm(float v) { return 1.0f / (1.0f + __expf(-v)); }
__device__ __forceinline__ float tanhfast(float v) {
    float e = __expf(2.0f * v);
    return 1.0f - 2.0f / (e + 1.0f);
}
__device__ __forceinline__ float seluf(float x) {
    // scale = 1.0507009873554805, scale*alpha = 1.7580993408473766
    return x > 0.0f ? 1.0507009873554805f * x : 1.7580993408473766f * (__expf(x) - 1.0f);
}

// Cubic B-spline basis, 8 bases, knots t_j = (j-3)*0.4 - 1, j=0..11 (matches jnp _knots)
__device__ __forceinline__ void bspline8(float xx, float* B) {
    float kn[12];
#pragma unroll
    for (int j = 0; j < 12; ++j) kn[j] = (float)(j - 3) * 0.4f - 1.0f;
    float b0[11];
#pragma unroll
    for (int j = 0; j < 11; ++j) b0[j] = (xx >= kn[j] && xx < kn[j + 1]) ? 1.0f : 0.0f;
    float b1[10];
#pragma unroll
    for (int j = 0; j < 10; ++j)
        b1[j] = (xx - kn[j]) * (1.0f / (kn[j + 1] - kn[j])) * b0[j] +
                (kn[j + 2] - xx) * (1.0f / (kn[j + 2] - kn[j + 1])) * b0[j + 1];
    float b2[9];
#pragma unroll
    for (int j = 0; j < 9; ++j)
        b2[j] = (xx - kn[j]) * (1.0f / (kn[j + 2] - kn[j])) * b1[j] +
                (kn[j + 3] - xx) * (1.0f / (kn[j + 3] - kn[j + 1])) * b1[j + 1];
#pragma unroll
    for (int j = 0; j < 8; ++j)
        B[j] = (xx - kn[j]) * (1.0f / (kn[j + 3] - kn[j])) * b2[j] +
               (kn[j + 4] - xx) * (1.0f / (kn[j + 4] - kn[j + 1])) * b2[j + 1];
}

// ---------------- S1: per-link load = sum_p traffic[p_idx] / (cap*1e9) ----------------
__global__ __launch_bounds__(256) void k_load(const int* __restrict__ p2l,
                                              const float* __restrict__ ft,
                                              const float* __restrict__ cap,
                                              float* __restrict__ load) {
    int gid = blockIdx.x * 256 + threadIdx.x;
    int link = gid >> 6;
    int lane = threadIdx.x & 63;
    const int2* b2 = (const int2*)(p2l + (size_t)link * PPL * 2);
    int2 v0 = b2[lane];
    int2 v1 = b2[lane + 64];
    float s = ft[v0.x] + ft[v1.x];
#pragma unroll
    for (int off = 32; off; off >>= 1) s += __shfl_xor(s, off);
    if (lane == 0) load[link] = s / (cap[link] * 1e9f);
}

// ---------------- S2: flow encoder -> path_state ----------------
__global__ __launch_bounds__(256) void k_flow_enc(
    const float* __restrict__ tr, const float* __restrict__ pk,
    const float* __restrict__ ppb, const float* __restrict__ bpb,
    const float* __restrict__ psz, const float* __restrict__ p90,
    const float* __restrict__ rate, const float* __restrict__ ipgm,
    const float* __restrict__ ibg, const float* __restrict__ ipgv,
    const float* __restrict__ ftype, const int* __restrict__ flen,
    const float* __restrict__ w1, const float* __restrict__ b1,
    const float* __restrict__ w2, const float* __restrict__ b2,
    float* __restrict__ ps) {
    __shared__ float sw1[13 * 16], sb1[16], sw2[256], sb2[16];
    int tid = threadIdx.x;
    if (tid < 208) sw1[tid] = w1[tid];
    sw2[tid] = w2[tid];
    if (tid < 16) { sb1[tid] = b1[tid]; sb2[tid] = b2[tid]; }
    __syncthreads();
    int f = blockIdx.x * 256 + tid;
    float feat[13];
    feat[0] = (tr[f] - 0.5f) * 2.0f;
    feat[1] = (pk[f] - 0.5f) * 2.0f;
    feat[2] = (ibg[f] - 0.5f) * 2.0f;
    feat[3] = (rate[f] - 0.5f) * 2.0f;
    feat[4] = (p90[f] - 0.5f) * 2.0f;
    feat[5] = (psz[f] - 0.5f) * 2.0f;
    feat[6] = (bpb[f] - 0.5f) * 2.0f;
    feat[7] = (ipgm[f] - 0.5f) * 2.0f;
    feat[8] = (ipgv[f] - 0.5f) * 2.0f;
    feat[9] = (ppb[f] - 0.5f) * 2.0f;
    feat[10] = (float)flen[f];
    float2 ft2 = ((const float2*)ftype)[f];
    feat[11] = ft2.x;
    feat[12] = ft2.y;
    float t1[16];
#pragma unroll
    for (int u = 0; u < 16; ++u) {
        float a = sb1[u];
#pragma unroll
        for (int i = 0; i < 13; ++i) a += feat[i] * sw1[i * 16 + u];
        t1[u] = seluf(a);
    }
    float out[16];
#pragma unroll
    for (int u = 0; u < 16; ++u) {
        float a = sb2[u];
#pragma unroll
        for (int i = 0; i < 16; ++i) a += t1[i] * sw2[i * 16 + u];
        out[u] = seluf(a);
    }
    float4* o4 = (float4*)(ps + (size_t)f * 16);
    const float4* s4 = (const float4*)out;
#pragma unroll
    for (int q = 0; q < 4; ++q) o4[q] = s4[q];
}

// ---------------- S3: link encoder -> link_state ----------------
__global__ __launch_bounds__(256) void k_link_enc(
    const float* __restrict__ cap, const float* __restrict__ load,
    const float* __restrict__ mll,
    const float* __restrict__ w1, const float* __restrict__ b1,
    const float* __restrict__ w2, const float* __restrict__ b2,
    float* __restrict__ ls) {
    int l = blockIdx.x * 256 + threadIdx.x;
    if (l >= NL) return;
    float f0 = (cap[l] - 5.0f) * 0.25f;
    float f1 = load[l];
    float f2 = f1 / mll[0];
    float f3 = 8.0f / 32768.0f;  // constant node-degree feature
    float t1[16];
#pragma unroll
    for (int u = 0; u < 16; ++u) {
        float a = b1[u] + f0 * w1[u] + f1 * w1[16 + u] + f2 * w1[32 + u] + f3 * w1[48 + u];
        t1[u] = seluf(a);
    }
    float out[16];
#pragma unroll
    for (int u = 0; u < 16; ++u) {
        float a = b2[u];
#pragma unroll
        for (int i = 0; i < 16; ++i) a += t1[i] * w2[i * 16 + u];
        out[u] = seluf(a);
    }
    float4* o4 = (float4*)(ls + (size_t)l * 16);
    const float4* s4 = (const float4*)out;
#pragma unroll
    for (int q = 0; q < 4; ++q) o4[q] = s4[q];
}

// ---------------- K1: path GRU over 8 hops, writes seq[f][0..8] ----------------
__global__ __launch_bounds__(256, 1) void k_path(
    const float* __restrict__ ls, const int* __restrict__ ltp,
    float* __restrict__ ps, float* __restrict__ seq,
    const float* __restrict__ gk, const float* __restrict__ grk,
    const float* __restrict__ gb) {
    __shared__ float sk[768], srk[768], sb[96];
    int tid = threadIdx.x;
#pragma unroll
    for (int i = tid; i < 768; i += 256) { sk[i] = gk[i]; srk[i] = grk[i]; }
    if (tid < 96) sb[tid] = gb[tid];
    __syncthreads();
    int f = blockIdx.x * 256 + tid;
    float h[16];
    {
        const float4* hv = (const float4*)(ps + (size_t)f * 16);
        float4* hr = (float4*)h;
        hr[0] = hv[0]; hr[1] = hv[1]; hr[2] = hv[2]; hr[3] = hv[3];
        float4* s0 = (float4*)(seq + (size_t)f * 9 * 16);
        s0[0] = hr[0]; s0[1] = hr[1]; s0[2] = hr[2]; s0[3] = hr[3];
    }
    for (int t = 0; t < 8; ++t) {
        int lk = ltp[(size_t)f * 8 + t];
        float x[16];
        {
            const float4* xv = (const float4*)(ls + (size_t)lk * 16);
            float4* xr = (float4*)x;
            xr[0] = xv[0]; xr[1] = xv[1]; xr[2] = xv[2]; xr[3] = xv[3];
        }
        float a[48], g[48];
#pragma unroll
        for (int u = 0; u < 48; ++u) { a[u] = sb[u]; g[u] = sb[48 + u]; }
#pragma unroll
        for (int i = 0; i < 16; ++i) {
            float xi = x[i], hi = h[i];
#pragma unroll
            for (int u = 0; u < 48; ++u) {
                a[u] += xi * sk[i * 48 + u];
                g[u] += hi * srk[i * 48 + u];
            }
        }
#pragma unroll
        for (int d = 0; d < 16; ++d) {
            float z = sigm(a[d] + g[d]);
            float r = sigm(a[16 + d] + g[16 + d]);
            float c = tanhfast(a[32 + d] + r * g[32 + d]);
            h[d] = z * h[d] + (1.0f - z) * c;
        }
        float4* so = (float4*)(seq + ((size_t)f * 9 + t + 1) * 16);
        const float4* hr = (const float4*)h;
        so[0] = hr[0]; so[1] = hr[1]; so[2] = hr[2]; so[3] = hr[3];
    }
    float4* po = (float4*)(ps + (size_t)f * 16);
    const float4* hr = (const float4*)h;
    po[0] = hr[0]; po[1] = hr[1]; po[2] = hr[2]; po[3] = hr[3];
}

// ---------------- K2: per-link attention message + link GRU ----------------
__global__ __launch_bounds__(128) void k_link_upd(
    const float* __restrict__ seq, const int* __restrict__ p2l,
    float* __restrict__ ls,
    const float* __restrict__ aw, const float* __restrict__ ab,
    const float* __restrict__ gk, const float* __restrict__ grk,
    const float* __restrict__ gb) {
    __shared__ float sW[256], sB[16], red[128][17], sh[16];
    int tid = threadIdx.x;
    int link = blockIdx.x;
    sW[tid] = aw[tid];
    sW[tid + 128] = aw[tid + 128];
    if (tid < 16) sB[tid] = ab[tid];
    __syncthreads();
    int2 pp = ((const int2*)p2l)[(size_t)link * PPL + tid];
    float pg[16];
    {
        const float4* pv = (const float4*)(seq + ((size_t)pp.x * 9 + pp.y) * 16);
        float4* pr = (float4*)pg;
        pr[0] = pv[0]; pr[1] = pv[1]; pr[2] = pv[2]; pr[3] = pv[3];
    }
    float at[16];
#pragma unroll
    for (int u = 0; u < 16; ++u) {
        float a = sB[u];
#pragma unroll
        for (int i = 0; i < 16; ++i) a += pg[i] * sW[i * 16 + u];
        at[u] = a > 0.0f ? a : 0.01f * a;
    }
    float mx = at[0];
#pragma unroll
    for (int u = 1; u < 16; ++u) mx = fmaxf(mx, at[u]);
    float e[16];
    float ssum = 0.0f;
#pragma unroll
    for (int u = 0; u < 16; ++u) { e[u] = __expf(at[u] - mx); ssum += e[u]; }
    float inv = 1.0f / ssum;
#pragma unroll
    for (int u = 0; u < 16; ++u) red[tid][u] = e[u] * inv * pg[u];
    __syncthreads();
    for (int s = 64; s > 0; s >>= 1) {
        if (tid < s) {
#pragma unroll
            for (int u = 0; u < 16; ++u) red[tid][u] += red[tid + s][u];
        }
        __syncthreads();
    }
    // msg = red[0][:]
    if (tid < 16) sh[tid] = ls[(size_t)link * 16 + tid];
    __syncthreads();
    if (tid < 16) {
        int d = tid;
        float az = gb[d], ar = gb[16 + d], ac = gb[32 + d];
        float gz = gb[48 + d], gr = gb[64 + d], gc = gb[80 + d];
#pragma unroll
        for (int i = 0; i < 16; ++i) {
            float mi = red[0][i];
            float hi = sh[i];
            az += mi * gk[i * 48 + d];
            ar += mi * gk[i * 48 + 16 + d];
            ac += mi * gk[i * 48 + 32 + d];
            gz += hi * grk[i * 48 + d];
            gr += hi * grk[i * 48 + 16 + d];
            gc += hi * grk[i * 48 + 32 + d];
        }
        float z = sigm(az + gz);
        float r = sigm(ar + gr);
        float c = tanhfast(ac + r * gc);
        ls[(size_t)link * 16 + d] = z * sh[d] + (1.0f - z) * c;
    }
}

// ---------------- K4: KAN readout + reduce over path positions ----------------
__global__ __launch_bounds__(256, 1) void k_kan(
    const float* __restrict__ seq, const int* __restrict__ ltp,
    const float* __restrict__ cap,
    const float* __restrict__ sp1, const float* __restrict__ ba1,
    const float* __restrict__ bi1,
    const float* __restrict__ sp2, const float* __restrict__ ba2,
    const float* __restrict__ bi2,
    float* __restrict__ out) {
    __shared__ float s1[2048], sba1[256], sbi1[16], s2[128], sba2[16];
    int tid = threadIdx.x;
#pragma unroll
    for (int i = tid; i < 2048; i += 256) s1[i] = sp1[i];
    sba1[tid] = ba1[tid];
    if (tid < 16) { sbi1[tid] = bi1[tid]; sba2[tid] = ba2[tid]; }
    if (tid < 128) s2[tid] = sp2[tid];
    __syncthreads();
    int gt = blockIdx.x * 256 + tid;  // f*8 + t
    int f = gt >> 3, t = gt & 7;
    float x[16];
    {
        const float4* xv = (const float4*)(seq + ((size_t)f * 9 + 1 + t) * 16);
        float4* xr = (float4*)x;
        xr[0] = xv[0]; xr[1] = xv[1]; xr[2] = xv[2]; xr[3] = xv[3];
    }
    float hh[16];
#pragma unroll
    for (int u = 0; u < 16; ++u) hh[u] = sbi1[u];
#pragma unroll
    for (int i = 0; i < 16; ++i) {
        float B[8];
        bspline8(x[i], B);
#pragma unroll
        for (int b = 0; b < 8; ++b) {
            float Bb = B[b];
#pragma unroll
            for (int u = 0; u < 16; ++u) hh[u] += Bb * s1[(i * 8 + b) * 16 + u];
        }
        float sil = x[i] * sigm(x[i]);
#pragma unroll
        for (int u = 0; u < 16; ++u) hh[u] += sil * sba1[i * 16 + u];
    }
    float occ = bi2[0];
#pragma unroll
    for (int i = 0; i < 16; ++i) {
        float B[8];
        bspline8(hh[i], B);
#pragma unroll
        for (int b = 0; b < 8; ++b) occ += B[b] * s2[i * 8 + b];
        occ += hh[i] * sigm(hh[i]) * sba2[i];
    }
    int lk = ltp[(size_t)f * 8 + t];
    float val = occ / cap[lk];
#pragma unroll
    for (int off = 4; off; off >>= 1) val += __shfl_xor(val, off, 8);
    if (t == 0) out[f] = val;
}

extern "C" void kernel_launch(void* const* d_in, const int* in_sizes, int n_in,
                              void* d_out, int out_size, void* d_ws, size_t ws_size,
                              hipStream_t stream) {
    const float* f_tr   = (const float*)d_in[0];
    const float* f_pk   = (const float*)d_in[1];
    const float* f_ppb  = (const float*)d_in[2];
    const float* f_bpb  = (const float*)d_in[3];
    const float* f_psz  = (const float*)d_in[4];
    const float* f_p90  = (const float*)d_in[5];
    const float* f_rate = (const float*)d_in[6];
    const float* f_ipgm = (const float*)d_in[7];
    const float* f_ibg  = (const float*)d_in[8];
    const float* f_ipgv = (const float*)d_in[9];
    const float* f_type = (const float*)d_in[10];
    const float* f_cap  = (const float*)d_in[11];
    const float* f_mll  = (const float*)d_in[12];
    const int*   i_flen = (const int*)d_in[13];
    // d_in[14] devices_to_link: only shapes used by reference -> constant feature
    const int*   i_ltp  = (const int*)d_in[15];
    const int*   i_p2l  = (const int*)d_in[16];
    const float* fe_w1 = (const float*)d_in[17];
    const float* fe_b1 = (const float*)d_in[18];
    const float* fe_w2 = (const float*)d_in[19];
    const float* fe_b2 = (const float*)d_in[20];
    const float* le_w1 = (const float*)d_in[21];
    const float* le_b1 = (const float*)d_in[22];
    const float* le_w2 = (const float*)d_in[23];
    const float* le_b2 = (const float*)d_in[24];
    const float* at_w  = (const float*)d_in[25];
    const float* at_b  = (const float*)d_in[26];
    const float* pg_k  = (const float*)d_in[27];
    const float* pg_rk = (const float*)d_in[28];
    const float* pg_b  = (const float*)d_in[29];
    const float* lg_k  = (const float*)d_in[30];
    const float* lg_rk = (const float*)d_in[31];
    const float* lg_b  = (const float*)d_in[32];
    const float* k1_sp = (const float*)d_in[33];
    const float* k1_ba = (const float*)d_in[34];
    const float* k1_bi = (const float*)d_in[35];
    const float* k2_sp = (const float*)d_in[36];
    const float* k2_ba = (const float*)d_in[37];
    const float* k2_bi = (const float*)d_in[38];

    float* ws = (float*)d_ws;
    float* seq  = ws;                              // NF*9*16 = 9,437,184 f
    float* ps   = seq + (size_t)NF * 9 * 16;       // NF*16   = 1,048,576 f
    float* ls   = ps + (size_t)NF * 16;            // NL*16   = 65,536 f
    float* load = ls + (size_t)NL * 16;            // NL      = 4,096 f
    float* out  = (float*)d_out;

    k_load<<<NL * 64 / 256, 256, 0, stream>>>(i_p2l, f_tr, f_cap, load);
    k_flow_enc<<<NF / 256, 256, 0, stream>>>(f_tr, f_pk, f_ppb, f_bpb, f_psz, f_p90,
                                             f_rate, f_ipgm, f_ibg, f_ipgv, f_type,
                                             i_flen, fe_w1, fe_b1, fe_w2, fe_b2, ps);
    k_link_enc<<<(NL + 255) / 256, 256, 0, stream>>>(f_cap, load, f_mll,
                                                     le_w1, le_b1, le_w2, le_b2, ls);
    for (int it = 0; it < 12; ++it) {
        k_path<<<NF / 256, 256, 0, stream>>>(ls, i_ltp, ps, seq, pg_k, pg_rk, pg_b);
        if (it < 11)  // last iteration's link update is dead in the reference
            k_link_upd<<<NL, 128, 0, stream>>>(seq, i_p2l, ls, at_w, at_b, lg_k, lg_rk, lg_b);
    }
    k_kan<<<(NF * PL) / 256, 256, 0, stream>>>(seq, i_ltp, f_cap, k1_sp, k1_ba, k1_bi,
                                               k2_sp, k2_ba, k2_bi, out);
}